// Round 1
// 3548.633 us; speedup vs baseline: 1.0396x; 1.0396x over previous
//
#include <hip/hip_runtime.h>
#include <hip/hip_bf16.h>
#include <math.h>

#define B_      32
#define NTOK    197
#define NPATCH  196
#define D_      768
#define DFF     3072
#define L_      12
#define NH      12
#define HD      64
#define NCLS    5
#define MTOK    (B_ * NTOK)      // 6304
#define MPAD    6400
#define MPATCH  (B_ * NPATCH)    // 6272
#define KPAD    224
#define KS_STR  72
#define VT_STR  232

typedef __attribute__((ext_vector_type(8))) short short8;
typedef __attribute__((ext_vector_type(4))) float floatx4;

static __device__ inline short f2bf(float f) {
  __hip_bfloat16 h = __float2bfloat16(f);
  short s; __builtin_memcpy(&s, &h, 2); return s;
}

// ---------------------------------------------------------------------------
__global__ __launch_bounds__(256) void cls_pos_kernel(
    const float* __restrict__ cls, const float* __restrict__ pos,
    float* __restrict__ tok) {
  int i = blockIdx.x * 256 + threadIdx.x;
  if (i < B_ * D_) {
    int b = i / D_, d = i % D_;
    tok[(size_t)b * NTOK * D_ + d] = cls[d] + pos[d];
  }
}

// ---------------------------------------------------------------------------
__global__ __launch_bounds__(256) void cvt_kernel(
    const float* __restrict__ src, short* __restrict__ dst, int n) {
  int i = blockIdx.x * 256 + threadIdx.x;
  if (i < n) dst[i] = f2bf(src[i]);
}

// ---------------------------------------------------------------------------
// all 4 weight transposes of one layer in one dispatch. 32x32 tiles.
// tile counts: qkv 24x72=1728, proj 24x24=576, fc1 24x96=2304, fc2 96x24=2304
__global__ __launch_bounds__(256) void wconv_all_kernel(
    const float* __restrict__ qw, const float* __restrict__ pw,
    const float* __restrict__ f1w, const float* __restrict__ f2w,
    short* __restrict__ wq, short* __restrict__ wp,
    short* __restrict__ w1, short* __restrict__ w2) {
  int id = blockIdx.x;
  const float* W; short* Wt; int K, N, t;
  if (id < 1728)      { W = qw;  Wt = wq; K = 768;  N = 2304; t = id; }
  else if (id < 2304) { W = pw;  Wt = wp; K = 768;  N = 768;  t = id - 1728; }
  else if (id < 4608) { W = f1w; Wt = w1; K = 768;  N = 3072; t = id - 2304; }
  else                { W = f2w; Wt = w2; K = 3072; N = 768;  t = id - 4608; }
  int ntn = N >> 5;
  int k0 = (t / ntn) * 32, n0 = (t % ntn) * 32;
  __shared__ float tt[32][33];
  int tid = threadIdx.x;
#pragma unroll
  for (int q = 0; q < 4; q++) {
    int e = q * 256 + tid;
    int rk = e >> 5, cn = e & 31;
    tt[rk][cn] = W[(size_t)(k0 + rk) * N + n0 + cn];
  }
  __syncthreads();
#pragma unroll
  for (int q = 0; q < 4; q++) {
    int e = q * 256 + tid;
    int rn = e >> 5, ck = e & 31;
    Wt[(size_t)(n0 + rn) * K + k0 + ck] = f2bf(tt[ck][rn]);
  }
}

// ---------------------------------------------------------------------------
__global__ __launch_bounds__(256) void im2col_kernel(
    const float* __restrict__ x, short* __restrict__ Abf) {
  int i = blockIdx.x * 256 + threadIdx.x;
  if (i >= MPATCH * D_) return;
  int row = i / D_, col = i % D_;
  int b = row / NPATCH, n = row % NPATCH;
  int ph = n / 14, pw = n % 14;
  int c = col >> 8, r = col & 255;
  int kh = r >> 4, kw = r & 15;
  Abf[i] = f2bf(x[(((size_t)b * 3 + c) * 224 + (ph * 16 + kh)) * 224 + (pw * 16 + kw)]);
}

// ---------------------------------------------------------------------------
__global__ __launch_bounds__(256) void patch_scatter_kernel(
    const float* __restrict__ po, const float* __restrict__ pos,
    float* __restrict__ tok) {
  int i = blockIdx.x * 256 + threadIdx.x;
  if (i >= MPATCH * D_) return;
  int row = i / D_, col = i % D_;
  int b = row / NPATCH, n = row % NPATCH;
  tok[((size_t)b * NTOK + 1 + n) * D_ + col] = po[i] + pos[(size_t)(1 + n) * D_ + col];
}

// ---------------------------------------------------------------------------
template <bool OBF>
__global__ __launch_bounds__(256) void ln_kernel(
    const float* __restrict__ in, void* __restrict__ out,
    const float* __restrict__ g, const float* __restrict__ bt,
    long rs_in) {
  int row = blockIdx.x;
  const float* xr = in + (size_t)row * rs_in;
  int tid = threadIdx.x;
  float v0 = xr[tid], v1 = xr[tid + 256], v2 = xr[tid + 512];
  float s = v0 + v1 + v2;
#pragma unroll
  for (int off = 32; off; off >>= 1) s += __shfl_xor(s, off);
  __shared__ float red1[4], red2[4];
  int wid = tid >> 6, lane = tid & 63;
  if (lane == 0) red1[wid] = s;
  __syncthreads();
  float mean = (red1[0] + red1[1] + red1[2] + red1[3]) * (1.f / 768.f);
  float d0 = v0 - mean, d1 = v1 - mean, d2 = v2 - mean;
  float s2 = d0 * d0 + d1 * d1 + d2 * d2;
#pragma unroll
  for (int off = 32; off; off >>= 1) s2 += __shfl_xor(s2, off);
  if (lane == 0) red2[wid] = s2;
  __syncthreads();
  float var = (red2[0] + red2[1] + red2[2] + red2[3]) * (1.f / 768.f);
  float rstd = rsqrtf(var + 1e-5f);
  float o0 = d0 * rstd * g[tid]       + bt[tid];
  float o1 = d1 * rstd * g[tid + 256] + bt[tid + 256];
  float o2 = d2 * rstd * g[tid + 512] + bt[tid + 512];
  if (OBF) {
    short* yr = (short*)out + (size_t)row * D_;
    yr[tid] = f2bf(o0); yr[tid + 256] = f2bf(o1); yr[tid + 512] = f2bf(o2);
  } else {
    float* yr = (float*)out + (size_t)row * D_;
    yr[tid] = o0; yr[tid + 256] = o1; yr[tid + 512] = o2;
  }
}

// ---------------------------------------------------------------------------
// Double-buffered bf16 MFMA GEMM: C = A[M,K] @ Wt[N,K]^T + bias (+res)(gelu).
// BM=128: 4 waves (2x2), BM=64: 2 waves (1x2); each wave owns 64x64 via 4x4
// grid of 16x16x32 MFMA. One barrier per K-iter; global_load_lds for tile
// k+1 is issued right after the barrier and completes during compute(k).
// SPLITK: gridDim.z slices of kslice each; fp32 partials to Cout + z*M*N,
// no bias/res/gelu (folded in the reduce kernel).
template <int BM, bool OBF, bool RES, bool GELU_, bool SPLITK = false>
__global__ __launch_bounds__(256) void gemm_db_kernel(
    const short* __restrict__ A, const short* __restrict__ Wt,
    const float* __restrict__ bias, const float* __restrict__ res,
    void* __restrict__ Cout, int M, int N, int K, int kslice) {
  constexpr int NBI = (BM == 128) ? 2 : 4;   // B-tile issues per wave
  __shared__ short As[2][BM * 32];
  __shared__ short Bs[2][128 * 32];
  const int tid = threadIdx.x;
  const int lane = tid & 63;
  const int wid = tid >> 6;
  const int wave_m = (BM == 128) ? (wid >> 1) : 0;
  const int wave_n = (BM == 128) ? (wid & 1) : wid;
  const int mbase = blockIdx.y * BM;
  const int nbase = blockIdx.x * 128;
  const int kbase = SPLITK ? blockIdx.z * kslice : 0;

  const int lrow = lane >> 2;
  const int kbg = (lane & 3) ^ ((lane >> 3) & 3);

  // A: wave wid stages rows [wid*32, wid*32+32), 2 chunks of 16 rows.
  const short* gA0 = A + (size_t)(mbase + wid * 32 + lrow) * K + kbase + kbg * 8;
  const short* gA1 = gA0 + 16 * (size_t)K;
  // B: BM=128 -> wave stages 32 rows (2 chunks); BM=64 -> 64 rows (4 chunks).
  const int brow0 = (BM == 128) ? (wid * 32) : (wid * 64);
  const short* gB[NBI];
  gB[0] = Wt + (size_t)(nbase + brow0 + lrow) * K + kbase + kbg * 8;
#pragma unroll
  for (int c = 1; c < NBI; c++) gB[c] = gB[0] + (size_t)c * 16 * K;

  typedef const __attribute__((address_space(1))) unsigned* gp_t;
  typedef __attribute__((address_space(3))) unsigned* lp_t;
  const int aoff = wid * 1024;
  const int boff = brow0 * 32;

  // prologue: stage tile 0 into buffer 0
  __builtin_amdgcn_global_load_lds((gp_t)(const void*)gA0, (lp_t)(void*)(&As[0][aoff]), 16, 0, 0);
  __builtin_amdgcn_global_load_lds((gp_t)(const void*)gA1, (lp_t)(void*)(&As[0][aoff + 512]), 16, 0, 0);
#pragma unroll
  for (int c = 0; c < NBI; c++)
    __builtin_amdgcn_global_load_lds((gp_t)(const void*)gB[c], (lp_t)(void*)(&Bs[0][boff + c * 512]), 16, 0, 0);

  floatx4 zero = {0.f, 0.f, 0.f, 0.f};
  floatx4 acc[4][4];
#pragma unroll
  for (int i = 0; i < 4; i++)
#pragma unroll
    for (int j = 0; j < 4; j++) acc[i][j] = zero;

  const int quad = lane >> 4;
  const int l15 = lane & 15;
  const int s = quad ^ ((l15 >> 1) & 3);

  const int niter = kslice >> 5;
  for (int it = 0; it < niter; it++) {
    const int cur = it & 1, nxt = cur ^ 1;
    __syncthreads();   // drains vmcnt: buf[cur] ready; lgkm: buf[nxt] reads done
    if (it + 1 < niter) {
      const int ks = (it + 1) << 5;
      __builtin_amdgcn_global_load_lds((gp_t)(const void*)(gA0 + ks), (lp_t)(void*)(&As[nxt][aoff]), 16, 0, 0);
      __builtin_amdgcn_global_load_lds((gp_t)(const void*)(gA1 + ks), (lp_t)(void*)(&As[nxt][aoff + 512]), 16, 0, 0);
#pragma unroll
      for (int c = 0; c < NBI; c++)
        __builtin_amdgcn_global_load_lds((gp_t)(const void*)(gB[c] + ks), (lp_t)(void*)(&Bs[nxt][boff + c * 512]), 16, 0, 0);
    }
    short8 a[4], b[4];
#pragma unroll
    for (int i = 0; i < 4; i++) {
      a[i] = *(const short8*)(&As[cur][(wave_m * 64 + i * 16 + l15) * 32 + s * 8]);
      b[i] = *(const short8*)(&Bs[cur][(wave_n * 64 + i * 16 + l15) * 32 + s * 8]);
    }
#pragma unroll
    for (int i = 0; i < 4; i++)
#pragma unroll
      for (int j = 0; j < 4; j++)
        acc[i][j] = __builtin_amdgcn_mfma_f32_16x16x32_bf16(a[i], b[j], acc[i][j], 0, 0, 0);
  }

  // epilogue: C/D layout col=lane&15, row=quad*4+reg
#pragma unroll
  for (int i = 0; i < 4; i++) {
    int gm0 = mbase + wave_m * 64 + i * 16 + quad * 4;
#pragma unroll
    for (int r = 0; r < 4; r++) {
      int gm = gm0 + r;
      if (gm >= M) continue;
#pragma unroll
      for (int j = 0; j < 4; j++) {
        int gn = nbase + wave_n * 64 + j * 16 + l15;
        if constexpr (SPLITK) {
          ((float*)Cout)[(size_t)blockIdx.z * M * N + (size_t)gm * N + gn] = acc[i][j][r];
        } else {
          float c = acc[i][j][r] + bias[gn];
          if (RES) c += res[(size_t)gm * N + gn];
          if (GELU_) c = 0.5f * c * (1.f + erff(c * 0.70710678118654752f));
          if (OBF) ((short*)Cout)[(size_t)gm * N + gn] = f2bf(c);
          else ((float*)Cout)[(size_t)gm * N + gn] = c;
        }
      }
    }
  }
}

// ---------------------------------------------------------------------------
// tok += bias + sum of 3 split-K fp32 partials. float4-vectorized.
__global__ __launch_bounds__(256) void fc2_reduce_kernel(
    const float* __restrict__ part, const float* __restrict__ bias,
    float* __restrict__ tok) {
  const size_t MN = (size_t)MTOK * D_;
  size_t i = ((size_t)blockIdx.x * 256 + threadIdx.x) * 4;
  if (i >= MN) return;
  floatx4 p0 = *(const floatx4*)(part + i);
  floatx4 p1 = *(const floatx4*)(part + i + MN);
  floatx4 p2 = *(const floatx4*)(part + i + 2 * MN);
  floatx4 t  = *(const floatx4*)(tok + i);
  int col = (int)(i % D_);
  floatx4 o;
#pragma unroll
  for (int r = 0; r < 4; r++) o[r] = t[r] + bias[col + r] + p0[r] + p1[r] + p2[r];
  *(floatx4*)(tok + i) = o;
}

// ---------------------------------------------------------------------------
// MFMA attention: one block (4 waves) per (b,h).
__global__ __launch_bounds__(256) void attn_mfma_kernel(
    const short* __restrict__ qkv, short* __restrict__ o) {
  __shared__ short Ks[KPAD * KS_STR];
  __shared__ short Vt[64 * VT_STR];
  __shared__ short Pw[4 * 16 * VT_STR];
  const int h = blockIdx.x % NH;
  const int b = blockIdx.x / NH;
  const int tid = threadIdx.x;
  const int lane = tid & 63, wid = tid >> 6;
  const size_t rowbase = (size_t)b * NTOK * (3 * D_);

  for (int it = 0; it < 7; it++) {
    int idx = it * 256 + tid;
    int dblk = idx / KPAD, key = idx % KPAD;
    int krow = key < NTOK ? key : NTOK - 1;
    const short* src = qkv + rowbase + (size_t)krow * (3 * D_) + h * HD;
    short8 kv = *(const short8*)(src + D_ + dblk * 8);
    *(short8*)(Ks + key * KS_STR + dblk * 8) = kv;
    short8 vv = *(const short8*)(src + 2 * D_ + dblk * 8);
#pragma unroll
    for (int i = 0; i < 8; i++) Vt[(dblk * 8 + i) * VT_STR + key] = vv[i];
  }
  __syncthreads();

  const int quad = lane >> 4, l15 = lane & 15;
  short* P = Pw + wid * 16 * VT_STR;
  const floatx4 zero = {0.f, 0.f, 0.f, 0.f};

  for (int qt = wid; qt < 14; qt += 4) {
    int qrow = qt * 16 + l15;
    int qr = qrow < NTOK ? qrow : NTOK - 1;
    const short* qbase = qkv + rowbase + (size_t)qr * (3 * D_) + h * HD;
    short8 a0 = *(const short8*)(qbase + quad * 8);
    short8 a1 = *(const short8*)(qbase + 32 + quad * 8);

    floatx4 s[14];
#pragma unroll
    for (int kt = 0; kt < 14; kt++) {
      const short* kb = Ks + (kt * 16 + l15) * KS_STR;
      short8 b0 = *(const short8*)(kb + quad * 8);
      short8 b1 = *(const short8*)(kb + 32 + quad * 8);
      floatx4 c = __builtin_amdgcn_mfma_f32_16x16x32_bf16(a0, b0, zero, 0, 0, 0);
      s[kt] = __builtin_amdgcn_mfma_f32_16x16x32_bf16(a1, b1, c, 0, 0, 0);
    }
#pragma unroll
    for (int kt = 0; kt < 14; kt++) {
      if (kt * 16 + l15 >= NTOK) {
#pragma unroll
        for (int r = 0; r < 4; r++) s[kt][r] = -1e30f;
      }
    }
    float mx[4] = {-1e30f, -1e30f, -1e30f, -1e30f};
#pragma unroll
    for (int kt = 0; kt < 14; kt++)
#pragma unroll
      for (int r = 0; r < 4; r++) mx[r] = fmaxf(mx[r], s[kt][r]);
#pragma unroll
    for (int off = 1; off < 16; off <<= 1)
#pragma unroll
      for (int r = 0; r < 4; r++) mx[r] = fmaxf(mx[r], __shfl_xor(mx[r], off));
    float lsum[4] = {0.f, 0.f, 0.f, 0.f};
#pragma unroll
    for (int kt = 0; kt < 14; kt++) {
#pragma unroll
      for (int r = 0; r < 4; r++) {
        float p = __expf(0.125f * (s[kt][r] - mx[r]));
        lsum[r] += p;
        P[(quad * 4 + r) * VT_STR + kt * 16 + l15] = f2bf(p);
      }
    }
#pragma unroll
    for (int off = 1; off < 16; off <<= 1)
#pragma unroll
      for (int r = 0; r < 4; r++) lsum[r] += __shfl_xor(lsum[r], off);
    float inv[4];
#pragma unroll
    for (int r = 0; r < 4; r++) inv[r] = 1.f / lsum[r];

    floatx4 oacc[4] = {zero, zero, zero, zero};
#pragma unroll
    for (int kk = 0; kk < 7; kk++) {
      short8 a = *(const short8*)(P + l15 * VT_STR + kk * 32 + quad * 8);
#pragma unroll
      for (int nt = 0; nt < 4; nt++) {
        short8 bv = *(const short8*)(Vt + (nt * 16 + l15) * VT_STR + kk * 32 + quad * 8);
        oacc[nt] = __builtin_amdgcn_mfma_f32_16x16x32_bf16(a, bv, oacc[nt], 0, 0, 0);
      }
    }
#pragma unroll
    for (int r = 0; r < 4; r++) {
      int q = qt * 16 + quad * 4 + r;
      if (q >= NTOK) continue;
      short* orow = o + ((size_t)(b * NTOK + q)) * D_ + h * HD;
#pragma unroll
      for (int nt = 0; nt < 4; nt++)
        orow[nt * 16 + l15] = f2bf(oacc[nt][r] * inv[r]);
    }
  }
}

// ---------------------------------------------------------------------------
__global__ __launch_bounds__(64) void head_kernel(
    const float* __restrict__ y, const float* __restrict__ hw,
    const float* __restrict__ hb, float* __restrict__ out) {
  int b = blockIdx.x;
  const float* yr = y + (size_t)b * D_;
  int lane = threadIdx.x;
  for (int j = 0; j < NCLS; j++) {
    float s = 0.f;
    for (int d = lane; d < D_; d += 64) s += yr[d] * hw[(size_t)d * NCLS + j];
#pragma unroll
    for (int off = 32; off; off >>= 1) s += __shfl_xor(s, off);
    if (lane == 0) out[b * NCLS + j] = s + hb[j];
  }
}

// ---------------------------------------------------------------------------
extern "C" void kernel_launch(void* const* d_in, const int* in_sizes, int n_in,
                              void* d_out, int out_size, void* d_ws, size_t ws_size,
                              hipStream_t stream) {
  const float* x        = (const float*)d_in[0];
  const float* conv_w   = (const float*)d_in[1];
  const float* conv_b   = (const float*)d_in[2];
  const float* cls_tok  = (const float*)d_in[3];
  const float* pos_emb  = (const float*)d_in[4];
  const float* ln1_g    = (const float*)d_in[5];
  const float* ln1_b    = (const float*)d_in[6];
  const float* qkv_w    = (const float*)d_in[7];
  const float* qkv_b    = (const float*)d_in[8];
  const float* proj_w   = (const float*)d_in[9];
  const float* proj_b   = (const float*)d_in[10];
  const float* ln2_g    = (const float*)d_in[11];
  const float* ln2_b    = (const float*)d_in[12];
  const float* fc1_w    = (const float*)d_in[13];
  const float* fc1_b    = (const float*)d_in[14];
  const float* fc2_w    = (const float*)d_in[15];
  const float* fc2_b    = (const float*)d_in[16];
  const float* norm_g   = (const float*)d_in[17];
  const float* norm_b   = (const float*)d_in[18];
  const float* head_w   = (const float*)d_in[19];
  const float* head_b   = (const float*)d_in[20];
  float* out = (float*)d_out;

  // ---- workspace layout ----
  char* p = (char*)d_ws;
  float* tok    = (float*)p;                 p += (size_t)MTOK * D_ * 4;
  short* y_bf   = (short*)p;                 p += (size_t)MPAD * D_ * 2;
  short* o_bf   = (short*)p;                 p += (size_t)MPAD * D_ * 2;
  short* h_bf   = (short*)p;                 p += (size_t)MPAD * DFF * 2;
  short* wt_qkv = (short*)p;                 p += (size_t)D_ * 3 * D_ * 2;
  short* wt_prj = (short*)p;                 p += (size_t)D_ * D_ * 2;
  short* wt_fc1 = (short*)p;                 p += (size_t)D_ * DFF * 2;
  short* wt_fc2 = (short*)p;                 p += (size_t)DFF * D_ * 2;
  short* cw_bf  = (short*)p;                 p += (size_t)D_ * D_ * 2;
  short* im_bf  = (short*)p;                 p += (size_t)MPAD * D_ * 2;
  float* big1   = (float*)p;                 p += (size_t)MTOK * 3 * D_ * 4;
  short* qkv_bf = (short*)big1;              // M x 2304 bf16 (layer loop)
  float* pout   = big1;                      // patch gemm out (pre-loop only)
  float* fc2_part = big1;                    // 3 x M x 768 fp32 split-K partials
  float* yf     = (float*)(p);               // 32x768 fp32 final-LN out

  // ---- patch embedding ----
  cvt_kernel<<<(D_ * D_ + 255) / 256, 256, 0, stream>>>(conv_w, cw_bf, D_ * D_);
  im2col_kernel<<<(MPATCH * D_ + 255) / 256, 256, 0, stream>>>(x, im_bf);
  cls_pos_kernel<<<(B_ * D_ + 255) / 256, 256, 0, stream>>>(cls_tok, pos_emb, tok);
  {
    dim3 g(D_ / 128, MPATCH / 64);  // 6 x 98
    gemm_db_kernel<64, false, false, false><<<g, 128, 0, stream>>>(
        im_bf, cw_bf, conv_b, nullptr, pout, MPATCH, D_, D_, D_);
  }
  patch_scatter_kernel<<<(MPATCH * D_ + 255) / 256, 256, 0, stream>>>(pout, pos_emb, tok);

  dim3 gQKV(3 * D_ / 128, (MTOK + 127) / 128);     // 18 x 50
  dim3 gPRJ(D_ / 128, (MTOK + 63) / 64);           // 6 x 99
  dim3 gFC1(DFF / 128, (MTOK + 127) / 128);        // 24 x 50
  dim3 gFC2(D_ / 128, (MTOK + 127) / 128, 3);      // 6 x 50 x 3 (split-K)

  for (int l = 0; l < L_; l++) {
    const float* l1g = ln1_g + l * D_;
    const float* l1b = ln1_b + l * D_;
    const float* qw  = qkv_w + (size_t)l * D_ * 3 * D_;
    const float* qb  = qkv_b + (size_t)l * 3 * D_;
    const float* pw  = proj_w + (size_t)l * D_ * D_;
    const float* pb  = proj_b + (size_t)l * D_;
    const float* l2g = ln2_g + l * D_;
    const float* l2b = ln2_b + l * D_;
    const float* f1w = fc1_w + (size_t)l * D_ * DFF;
    const float* f1b = fc1_b + (size_t)l * DFF;
    const float* f2w = fc2_w + (size_t)l * DFF * D_;
    const float* f2b = fc2_b + (size_t)l * D_;

    wconv_all_kernel<<<6912, 256, 0, stream>>>(qw, pw, f1w, f2w,
                                               wt_qkv, wt_prj, wt_fc1, wt_fc2);

    ln_kernel<true><<<MTOK, 256, 0, stream>>>(tok, y_bf, l1g, l1b, D_);
    gemm_db_kernel<128, true, false, false><<<gQKV, 256, 0, stream>>>(
        y_bf, wt_qkv, qb, nullptr, qkv_bf, MTOK, 3 * D_, D_, D_);
    attn_mfma_kernel<<<B_ * NH, 256, 0, stream>>>(qkv_bf, o_bf);
    gemm_db_kernel<64, false, true, false><<<gPRJ, 128, 0, stream>>>(
        o_bf, wt_prj, pb, tok, tok, MTOK, D_, D_, D_);
    ln_kernel<true><<<MTOK, 256, 0, stream>>>(tok, y_bf, l2g, l2b, D_);
    gemm_db_kernel<128, true, false, true><<<gFC1, 256, 0, stream>>>(
        y_bf, wt_fc1, f1b, nullptr, h_bf, MTOK, DFF, D_, D_);
    // FC2: split-K=3 over K=3072 -> fp32 partials, then fused reduce
    gemm_db_kernel<128, false, false, false, true><<<gFC2, 256, 0, stream>>>(
        h_bf, wt_fc2, nullptr, nullptr, fc2_part, MTOK, D_, DFF, 1024);
    fc2_reduce_kernel<<<(MTOK * D_ / 4 + 255) / 256, 256, 0, stream>>>(
        fc2_part, f2b, tok);
  }

  ln_kernel<false><<<B_, 256, 0, stream>>>(tok, yf, norm_g, norm_b, (long)NTOK * D_);
  head_kernel<<<B_, 64, 0, stream>>>(yf, head_w, head_b, out);
}

// Round 2
// 3545.074 us; speedup vs baseline: 1.0407x; 1.0010x over previous
//
#include <hip/hip_runtime.h>
#include <hip/hip_bf16.h>
#include <math.h>

#define B_      32
#define NTOK    197
#define NPATCH  196
#define D_      768
#define DFF     3072
#define L_      12
#define NH      12
#define HD      64
#define NCLS    5
#define MTOK    (B_ * NTOK)      // 6304
#define MPAD    6400
#define MPATCH  (B_ * NPATCH)    // 6272
#define KPAD    224
#define KS_STR  72
#define VT_STR  232

typedef __attribute__((ext_vector_type(8))) short short8;
typedef __attribute__((ext_vector_type(4))) float floatx4;

static __device__ inline short f2bf(float f) {
  __hip_bfloat16 h = __float2bfloat16(f);
  short s; __builtin_memcpy(&s, &h, 2); return s;
}

// ---------------------------------------------------------------------------
__global__ __launch_bounds__(256) void cls_pos_kernel(
    const float* __restrict__ cls, const float* __restrict__ pos,
    float* __restrict__ tok) {
  int i = blockIdx.x * 256 + threadIdx.x;
  if (i < B_ * D_) {
    int b = i / D_, d = i % D_;
    tok[(size_t)b * NTOK * D_ + d] = cls[d] + pos[d];
  }
}

// ---------------------------------------------------------------------------
__global__ __launch_bounds__(256) void cvt_kernel(
    const float* __restrict__ src, short* __restrict__ dst, int n) {
  int i = blockIdx.x * 256 + threadIdx.x;
  if (i < n) dst[i] = f2bf(src[i]);
}

// ---------------------------------------------------------------------------
// all 4 weight transposes of one layer in one dispatch. 32x32 tiles.
__global__ __launch_bounds__(256) void wconv_all_kernel(
    const float* __restrict__ qw, const float* __restrict__ pw,
    const float* __restrict__ f1w, const float* __restrict__ f2w,
    short* __restrict__ wq, short* __restrict__ wp,
    short* __restrict__ w1, short* __restrict__ w2) {
  int id = blockIdx.x;
  const float* W; short* Wt; int K, N, t;
  if (id < 1728)      { W = qw;  Wt = wq; K = 768;  N = 2304; t = id; }
  else if (id < 2304) { W = pw;  Wt = wp; K = 768;  N = 768;  t = id - 1728; }
  else if (id < 4608) { W = f1w; Wt = w1; K = 768;  N = 3072; t = id - 2304; }
  else                { W = f2w; Wt = w2; K = 3072; N = 768;  t = id - 4608; }
  int ntn = N >> 5;
  int k0 = (t / ntn) * 32, n0 = (t % ntn) * 32;
  __shared__ float tt[32][33];
  int tid = threadIdx.x;
#pragma unroll
  for (int q = 0; q < 4; q++) {
    int e = q * 256 + tid;
    int rk = e >> 5, cn = e & 31;
    tt[rk][cn] = W[(size_t)(k0 + rk) * N + n0 + cn];
  }
  __syncthreads();
#pragma unroll
  for (int q = 0; q < 4; q++) {
    int e = q * 256 + tid;
    int rn = e >> 5, ck = e & 31;
    Wt[(size_t)(n0 + rn) * K + k0 + ck] = f2bf(tt[ck][rn]);
  }
}

// ---------------------------------------------------------------------------
__global__ __launch_bounds__(256) void im2col_kernel(
    const float* __restrict__ x, short* __restrict__ Abf) {
  int i = blockIdx.x * 256 + threadIdx.x;
  if (i >= MPATCH * D_) return;
  int row = i / D_, col = i % D_;
  int b = row / NPATCH, n = row % NPATCH;
  int ph = n / 14, pw = n % 14;
  int c = col >> 8, r = col & 255;
  int kh = r >> 4, kw = r & 15;
  Abf[i] = f2bf(x[(((size_t)b * 3 + c) * 224 + (ph * 16 + kh)) * 224 + (pw * 16 + kw)]);
}

// ---------------------------------------------------------------------------
__global__ __launch_bounds__(256) void patch_scatter_kernel(
    const float* __restrict__ po, const float* __restrict__ pos,
    float* __restrict__ tok) {
  int i = blockIdx.x * 256 + threadIdx.x;
  if (i >= MPATCH * D_) return;
  int row = i / D_, col = i % D_;
  int b = row / NPATCH, n = row % NPATCH;
  tok[((size_t)b * NTOK + 1 + n) * D_ + col] = po[i] + pos[(size_t)(1 + n) * D_ + col];
}

// ---------------------------------------------------------------------------
template <bool OBF>
__global__ __launch_bounds__(256) void ln_kernel(
    const float* __restrict__ in, void* __restrict__ out,
    const float* __restrict__ g, const float* __restrict__ bt,
    long rs_in) {
  int row = blockIdx.x;
  const float* xr = in + (size_t)row * rs_in;
  int tid = threadIdx.x;
  float v0 = xr[tid], v1 = xr[tid + 256], v2 = xr[tid + 512];
  float s = v0 + v1 + v2;
#pragma unroll
  for (int off = 32; off; off >>= 1) s += __shfl_xor(s, off);
  __shared__ float red1[4], red2[4];
  int wid = tid >> 6, lane = tid & 63;
  if (lane == 0) red1[wid] = s;
  __syncthreads();
  float mean = (red1[0] + red1[1] + red1[2] + red1[3]) * (1.f / 768.f);
  float d0 = v0 - mean, d1 = v1 - mean, d2 = v2 - mean;
  float s2 = d0 * d0 + d1 * d1 + d2 * d2;
#pragma unroll
  for (int off = 32; off; off >>= 1) s2 += __shfl_xor(s2, off);
  if (lane == 0) red2[wid] = s2;
  __syncthreads();
  float var = (red2[0] + red2[1] + red2[2] + red2[3]) * (1.f / 768.f);
  float rstd = rsqrtf(var + 1e-5f);
  float o0 = d0 * rstd * g[tid]       + bt[tid];
  float o1 = d1 * rstd * g[tid + 256] + bt[tid + 256];
  float o2 = d2 * rstd * g[tid + 512] + bt[tid + 512];
  if (OBF) {
    short* yr = (short*)out + (size_t)row * D_;
    yr[tid] = f2bf(o0); yr[tid + 256] = f2bf(o1); yr[tid + 512] = f2bf(o2);
  } else {
    float* yr = (float*)out + (size_t)row * D_;
    yr[tid] = o0; yr[tid + 256] = o1; yr[tid + 512] = o2;
  }
}

// ---------------------------------------------------------------------------
// 256x256 8-phase-schedule GEMM (T3+T4+T5): C = A[M,K] @ Wt[N,K]^T + bias.
// 512 thr = 8 waves (2M x 4N), each wave owns 128x64 via acc[8][4] of
// 16x16x32 MFMA. BK=64 = two 32-k slabs. LDS 128KB double-buffered, staged
// via global_load_lds with the XOR k-chunk swizzle (conflict-free, measured).
// Per K-tile: 4 phases, each {stage 1 quarter of next tile | ds_read 4-8 |
// raw s_barrier | 16 MFMA in setprio(1) | s_barrier}. Counted vmcnt(6) at
// phases 0/2 only (slab k0/k1 resident; 3 quarters stay in flight) — loads
// cross barriers, never drained to 0 in steady state.
template <bool GELU_>
__global__ __launch_bounds__(512, 2) void gemm256_kernel(
    const short* __restrict__ A, const short* __restrict__ Wt,
    const float* __restrict__ bias, short* __restrict__ Cout,
    int M, int N, int K) {
  __shared__ short lds[2 * 32768];   // [buf][A 16384 | B 16384], slab=8192
  const int tid = threadIdx.x;
  const int lane = tid & 63;
  const int w = tid >> 6;
  const int wave_m = w >> 2;         // 0..1
  const int wave_n = w & 3;          // 0..3
  const int mbase = blockIdx.y * 256;
  const int nbase = blockIdx.x * 256;

  const int lrow = lane >> 2;
  const int kbg = (lane & 3) ^ ((lane >> 3) & 3);
  const int quad = lane >> 4;
  const int l15 = lane & 15;
  const int s = quad ^ ((l15 >> 1) & 3);

  // staging source pointers: hi=0 -> rows [w*16,w*16+16), hi=1 -> +128 rows
  const short* pAh[2];
  pAh[0] = A + (size_t)(mbase + w * 16 + lrow) * K + kbg * 8;
  pAh[1] = pAh[0] + (size_t)128 * K;
  const short* pBh[2];
  pBh[0] = Wt + (size_t)(nbase + w * 16 + lrow) * K + kbg * 8;
  pBh[1] = pBh[0] + (size_t)128 * K;

  typedef const __attribute__((address_space(1))) unsigned* gp_t;
  typedef __attribute__((address_space(3))) unsigned* lp_t;

  // quarter Q of a K-tile: hi=Q&1 (row half), ks=Q>>1 (k slab); 2 loads/wave
#define STAGE(BUFOFF, Q, KOFF) do {                                          \
    const int hi_ = (Q) & 1, ks_ = (Q) >> 1;                                 \
    __builtin_amdgcn_global_load_lds(                                        \
        (gp_t)(const void*)(pAh[hi_] + (KOFF) + ks_ * 32),                   \
        (lp_t)(void*)(&lds[(BUFOFF) + ks_ * 8192 + (hi_ * 8 + w) * 512]),    \
        16, 0, 0);                                                           \
    __builtin_amdgcn_global_load_lds(                                        \
        (gp_t)(const void*)(pBh[hi_] + (KOFF) + ks_ * 32),                   \
        (lp_t)(void*)(&lds[(BUFOFF) + 16384 + ks_ * 8192 + (hi_ * 8 + w) * 512]), \
        16, 0, 0);                                                           \
  } while (0)

  const int abase = (wave_m * 128 + l15) * 32 + s * 8;
  const int bbase = 16384 + (wave_n * 64 + l15) * 32 + s * 8;

#define LDA4(DST, CUROFF, KS, MF0)                                           \
  _Pragma("unroll") for (int m_ = 0; m_ < 4; m_++)                           \
      DST[m_] = *(const short8*)&lds[(CUROFF) + (KS) * 8192 + abase + ((MF0) + m_) * 512];
#define LDB4(DST, CUROFF, KS)                                                \
  _Pragma("unroll") for (int n_ = 0; n_ < 4; n_++)                           \
      DST[n_] = *(const short8*)&lds[(CUROFF) + (KS) * 8192 + bbase + n_ * 512];
#define MFMA16(MF0, AFR, BFR) do {                                           \
    __builtin_amdgcn_s_setprio(1);                                           \
    _Pragma("unroll") for (int m_ = 0; m_ < 4; m_++)                         \
      _Pragma("unroll") for (int n_ = 0; n_ < 4; n_++)                       \
        acc[(MF0) + m_][n_] = __builtin_amdgcn_mfma_f32_16x16x32_bf16(       \
            AFR[m_], BFR[n_], acc[(MF0) + m_][n_], 0, 0, 0);                 \
    __builtin_amdgcn_s_setprio(0);                                           \
  } while (0)

  floatx4 acc[8][4];
#pragma unroll
  for (int i = 0; i < 8; i++)
#pragma unroll
    for (int j = 0; j < 4; j++) acc[i][j] = floatx4{0.f, 0.f, 0.f, 0.f};

  // prologue: stage all 4 quarters of tile 0 into buf 0 (8 loads, in order)
  STAGE(0, 0, 0); STAGE(0, 1, 0); STAGE(0, 2, 0); STAGE(0, 3, 0);

  const int NT = K >> 6;
#pragma unroll 1
  for (int kt = 0; kt < NT; kt++) {
    const int cur = (kt & 1) * 32768;
    const int nxtb = 32768 - cur;
    const int koffn = (kt + 1) << 6;
    const bool pref = (kt + 1 < NT);
    short8 af[4], bf4[4];

    // ---- phase 0: slab k0, mf 0-3 ----
    if (pref) { STAGE(nxtb, 0, koffn); asm volatile("s_waitcnt vmcnt(6)" ::: "memory"); }
    else      { asm volatile("s_waitcnt vmcnt(4)" ::: "memory"); }
    __builtin_amdgcn_s_barrier();
    asm volatile("" ::: "memory");
    LDB4(bf4, cur, 0);
    LDA4(af, cur, 0, 0);
    MFMA16(0, af, bf4);
    __builtin_amdgcn_s_barrier();

    // ---- phase 1: slab k0, mf 4-7 ----
    if (pref) STAGE(nxtb, 1, koffn);
    LDA4(af, cur, 0, 4);
    __builtin_amdgcn_s_barrier();
    asm volatile("" ::: "memory");
    MFMA16(4, af, bf4);
    __builtin_amdgcn_s_barrier();

    // ---- phase 2: slab k1, mf 0-3 ----
    if (pref) { STAGE(nxtb, 2, koffn); asm volatile("s_waitcnt vmcnt(6)" ::: "memory"); }
    else      { asm volatile("s_waitcnt vmcnt(0)" ::: "memory"); }
    __builtin_amdgcn_s_barrier();
    asm volatile("" ::: "memory");
    LDB4(bf4, cur, 1);
    LDA4(af, cur, 1, 0);
    MFMA16(0, af, bf4);
    __builtin_amdgcn_s_barrier();

    // ---- phase 3: slab k1, mf 4-7 ----
    if (pref) STAGE(nxtb, 3, koffn);
    LDA4(af, cur, 1, 4);
    __builtin_amdgcn_s_barrier();
    asm volatile("" ::: "memory");
    MFMA16(4, af, bf4);
    __builtin_amdgcn_s_barrier();
  }
#undef STAGE
#undef LDA4
#undef LDB4
#undef MFMA16

  // epilogue: C/D layout col=lane&15, row=quad*4+reg
  float bs[4];
#pragma unroll
  for (int nf = 0; nf < 4; nf++) bs[nf] = bias[nbase + wave_n * 64 + nf * 16 + l15];
#pragma unroll
  for (int mf = 0; mf < 8; mf++) {
    int gm0 = mbase + wave_m * 128 + mf * 16 + quad * 4;
#pragma unroll
    for (int r = 0; r < 4; r++) {
      int gm = gm0 + r;
      if (gm >= M) continue;
      short* crow = Cout + (size_t)gm * N + nbase + wave_n * 64;
#pragma unroll
      for (int nf = 0; nf < 4; nf++) {
        float c = acc[mf][nf][r] + bs[nf];
        if (GELU_) c = 0.5f * c * (1.f + erff(c * 0.70710678118654752f));
        crow[nf * 16 + l15] = f2bf(c);
      }
    }
  }
}

// ---------------------------------------------------------------------------
// Double-buffered bf16 MFMA GEMM (2-barrier structure) for the small-N ops.
template <int BM, bool OBF, bool RES, bool GELU_, bool SPLITK = false>
__global__ __launch_bounds__(256) void gemm_db_kernel(
    const short* __restrict__ A, const short* __restrict__ Wt,
    const float* __restrict__ bias, const float* __restrict__ res,
    void* __restrict__ Cout, int M, int N, int K, int kslice) {
  constexpr int NBI = (BM == 128) ? 2 : 4;   // B-tile issues per wave
  __shared__ short As[2][BM * 32];
  __shared__ short Bs[2][128 * 32];
  const int tid = threadIdx.x;
  const int lane = tid & 63;
  const int wid = tid >> 6;
  const int wave_m = (BM == 128) ? (wid >> 1) : 0;
  const int wave_n = (BM == 128) ? (wid & 1) : wid;
  const int mbase = blockIdx.y * BM;
  const int nbase = blockIdx.x * 128;
  const int kbase = SPLITK ? blockIdx.z * kslice : 0;

  const int lrow = lane >> 2;
  const int kbg = (lane & 3) ^ ((lane >> 3) & 3);

  const short* gA0 = A + (size_t)(mbase + wid * 32 + lrow) * K + kbase + kbg * 8;
  const short* gA1 = gA0 + 16 * (size_t)K;
  const int brow0 = (BM == 128) ? (wid * 32) : (wid * 64);
  const short* gB[NBI];
  gB[0] = Wt + (size_t)(nbase + brow0 + lrow) * K + kbase + kbg * 8;
#pragma unroll
  for (int c = 1; c < NBI; c++) gB[c] = gB[0] + (size_t)c * 16 * K;

  typedef const __attribute__((address_space(1))) unsigned* gp_t;
  typedef __attribute__((address_space(3))) unsigned* lp_t;
  const int aoff = wid * 1024;
  const int boff = brow0 * 32;

  __builtin_amdgcn_global_load_lds((gp_t)(const void*)gA0, (lp_t)(void*)(&As[0][aoff]), 16, 0, 0);
  __builtin_amdgcn_global_load_lds((gp_t)(const void*)gA1, (lp_t)(void*)(&As[0][aoff + 512]), 16, 0, 0);
#pragma unroll
  for (int c = 0; c < NBI; c++)
    __builtin_amdgcn_global_load_lds((gp_t)(const void*)gB[c], (lp_t)(void*)(&Bs[0][boff + c * 512]), 16, 0, 0);

  floatx4 zero = {0.f, 0.f, 0.f, 0.f};
  floatx4 acc[4][4];
#pragma unroll
  for (int i = 0; i < 4; i++)
#pragma unroll
    for (int j = 0; j < 4; j++) acc[i][j] = zero;

  const int quad = lane >> 4;
  const int l15 = lane & 15;
  const int s = quad ^ ((l15 >> 1) & 3);

  const int niter = kslice >> 5;
  for (int it = 0; it < niter; it++) {
    const int cur = it & 1, nxt = cur ^ 1;
    __syncthreads();
    if (it + 1 < niter) {
      const int ks = (it + 1) << 5;
      __builtin_amdgcn_global_load_lds((gp_t)(const void*)(gA0 + ks), (lp_t)(void*)(&As[nxt][aoff]), 16, 0, 0);
      __builtin_amdgcn_global_load_lds((gp_t)(const void*)(gA1 + ks), (lp_t)(void*)(&As[nxt][aoff + 512]), 16, 0, 0);
#pragma unroll
      for (int c = 0; c < NBI; c++)
        __builtin_amdgcn_global_load_lds((gp_t)(const void*)(gB[c] + ks), (lp_t)(void*)(&Bs[nxt][boff + c * 512]), 16, 0, 0);
    }
    short8 a[4], b[4];
#pragma unroll
    for (int i = 0; i < 4; i++) {
      a[i] = *(const short8*)(&As[cur][(wave_m * 64 + i * 16 + l15) * 32 + s * 8]);
      b[i] = *(const short8*)(&Bs[cur][(wave_n * 64 + i * 16 + l15) * 32 + s * 8]);
    }
#pragma unroll
    for (int i = 0; i < 4; i++)
#pragma unroll
      for (int j = 0; j < 4; j++)
        acc[i][j] = __builtin_amdgcn_mfma_f32_16x16x32_bf16(a[i], b[j], acc[i][j], 0, 0, 0);
  }

#pragma unroll
  for (int i = 0; i < 4; i++) {
    int gm0 = mbase + wave_m * 64 + i * 16 + quad * 4;
#pragma unroll
    for (int r = 0; r < 4; r++) {
      int gm = gm0 + r;
      if (gm >= M) continue;
#pragma unroll
      for (int j = 0; j < 4; j++) {
        int gn = nbase + wave_n * 64 + j * 16 + l15;
        if constexpr (SPLITK) {
          ((float*)Cout)[(size_t)blockIdx.z * M * N + (size_t)gm * N + gn] = acc[i][j][r];
        } else {
          float c = acc[i][j][r] + bias[gn];
          if (RES) c += res[(size_t)gm * N + gn];
          if (GELU_) c = 0.5f * c * (1.f + erff(c * 0.70710678118654752f));
          if (OBF) ((short*)Cout)[(size_t)gm * N + gn] = f2bf(c);
          else ((float*)Cout)[(size_t)gm * N + gn] = c;
        }
      }
    }
  }
}

// ---------------------------------------------------------------------------
// tok += bias + sum of 3 split-K fp32 partials. float4-vectorized.
__global__ __launch_bounds__(256) void fc2_reduce_kernel(
    const float* __restrict__ part, const float* __restrict__ bias,
    float* __restrict__ tok) {
  const size_t MN = (size_t)MTOK * D_;
  size_t i = ((size_t)blockIdx.x * 256 + threadIdx.x) * 4;
  if (i >= MN) return;
  floatx4 p0 = *(const floatx4*)(part + i);
  floatx4 p1 = *(const floatx4*)(part + i + MN);
  floatx4 p2 = *(const floatx4*)(part + i + 2 * MN);
  floatx4 t  = *(const floatx4*)(tok + i);
  int col = (int)(i % D_);
  floatx4 o;
#pragma unroll
  for (int r = 0; r < 4; r++) o[r] = t[r] + bias[col + r] + p0[r] + p1[r] + p2[r];
  *(floatx4*)(tok + i) = o;
}

// ---------------------------------------------------------------------------
// MFMA attention: one block (4 waves) per (b,h).
__global__ __launch_bounds__(256) void attn_mfma_kernel(
    const short* __restrict__ qkv, short* __restrict__ o) {
  __shared__ short Ks[KPAD * KS_STR];
  __shared__ short Vt[64 * VT_STR];
  __shared__ short Pw[4 * 16 * VT_STR];
  const int h = blockIdx.x % NH;
  const int b = blockIdx.x / NH;
  const int tid = threadIdx.x;
  const int lane = tid & 63, wid = tid >> 6;
  const size_t rowbase = (size_t)b * NTOK * (3 * D_);

  for (int it = 0; it < 7; it++) {
    int idx = it * 256 + tid;
    int dblk = idx / KPAD, key = idx % KPAD;
    int krow = key < NTOK ? key : NTOK - 1;
    const short* src = qkv + rowbase + (size_t)krow * (3 * D_) + h * HD;
    short8 kv = *(const short8*)(src + D_ + dblk * 8);
    *(short8*)(Ks + key * KS_STR + dblk * 8) = kv;
    short8 vv = *(const short8*)(src + 2 * D_ + dblk * 8);
#pragma unroll
    for (int i = 0; i < 8; i++) Vt[(dblk * 8 + i) * VT_STR + key] = vv[i];
  }
  __syncthreads();

  const int quad = lane >> 4, l15 = lane & 15;
  short* P = Pw + wid * 16 * VT_STR;
  const floatx4 zero = {0.f, 0.f, 0.f, 0.f};

  for (int qt = wid; qt < 14; qt += 4) {
    int qrow = qt * 16 + l15;
    int qr = qrow < NTOK ? qrow : NTOK - 1;
    const short* qbase = qkv + rowbase + (size_t)qr * (3 * D_) + h * HD;
    short8 a0 = *(const short8*)(qbase + quad * 8);
    short8 a1 = *(const short8*)(qbase + 32 + quad * 8);

    floatx4 s[14];
#pragma unroll
    for (int kt = 0; kt < 14; kt++) {
      const short* kb = Ks + (kt * 16 + l15) * KS_STR;
      short8 b0 = *(const short8*)(kb + quad * 8);
      short8 b1 = *(const short8*)(kb + 32 + quad * 8);
      floatx4 c = __builtin_amdgcn_mfma_f32_16x16x32_bf16(a0, b0, zero, 0, 0, 0);
      s[kt] = __builtin_amdgcn_mfma_f32_16x16x32_bf16(a1, b1, c, 0, 0, 0);
    }
#pragma unroll
    for (int kt = 0; kt < 14; kt++) {
      if (kt * 16 + l15 >= NTOK) {
#pragma unroll
        for (int r = 0; r < 4; r++) s[kt][r] = -1e30f;
      }
    }
    float mx[4] = {-1e30f, -1e30f, -1e30f, -1e30f};
#pragma unroll
    for (int kt = 0; kt < 14; kt++)
#pragma unroll
      for (int r = 0; r < 4; r++) mx[r] = fmaxf(mx[r], s[kt][r]);
#pragma unroll
    for (int off = 1; off < 16; off <<= 1)
#pragma unroll
      for (int r = 0; r < 4; r++) mx[r] = fmaxf(mx[r], __shfl_xor(mx[r], off));
    float lsum[4] = {0.f, 0.f, 0.f, 0.f};
#pragma unroll
    for (int kt = 0; kt < 14; kt++) {
#pragma unroll
      for (int r = 0; r < 4; r++) {
        float p = __expf(0.125f * (s[kt][r] - mx[r]));
        lsum[r] += p;
        P[(quad * 4 + r) * VT_STR + kt * 16 + l15] = f2bf(p);
      }
    }
#pragma unroll
    for (int off = 1; off < 16; off <<= 1)
#pragma unroll
      for (int r = 0; r < 4; r++) lsum[r] += __shfl_xor(lsum[r], off);
    float inv[4];
#pragma unroll
    for (int r = 0; r < 4; r++) inv[r] = 1.f / lsum[r];

    floatx4 oacc[4] = {zero, zero, zero, zero};
#pragma unroll
    for (int kk = 0; kk < 7; kk++) {
      short8 a = *(const short8*)(P + l15 * VT_STR + kk * 32 + quad * 8);
#pragma unroll
      for (int nt = 0; nt < 4; nt++) {
        short8 bv = *(const short8*)(Vt + (nt * 16 + l15) * VT_STR + kk * 32 + quad * 8);
        oacc[nt] = __builtin_amdgcn_mfma_f32_16x16x32_bf16(a, bv, oacc[nt], 0, 0, 0);
      }
    }
#pragma unroll
    for (int r = 0; r < 4; r++) {
      int q = qt * 16 + quad * 4 + r;
      if (q >= NTOK) continue;
      short* orow = o + ((size_t)(b * NTOK + q)) * D_ + h * HD;
#pragma unroll
      for (int nt = 0; nt < 4; nt++)
        orow[nt * 16 + l15] = f2bf(oacc[nt][r] * inv[r]);
    }
  }
}

// ---------------------------------------------------------------------------
__global__ __launch_bounds__(64) void head_kernel(
    const float* __restrict__ y, const float* __restrict__ hw,
    const float* __restrict__ hb, float* __restrict__ out) {
  int b = blockIdx.x;
  const float* yr = y + (size_t)b * D_;
  int lane = threadIdx.x;
  for (int j = 0; j < NCLS; j++) {
    float s = 0.f;
    for (int d = lane; d < D_; d += 64) s += yr[d] * hw[(size_t)d * NCLS + j];
#pragma unroll
    for (int off = 32; off; off >>= 1) s += __shfl_xor(s, off);
    if (lane == 0) out[b * NCLS + j] = s + hb[j];
  }
}

// ---------------------------------------------------------------------------
extern "C" void kernel_launch(void* const* d_in, const int* in_sizes, int n_in,
                              void* d_out, int out_size, void* d_ws, size_t ws_size,
                              hipStream_t stream) {
  const float* x        = (const float*)d_in[0];
  const float* conv_w   = (const float*)d_in[1];
  const float* conv_b   = (const float*)d_in[2];
  const float* cls_tok  = (const float*)d_in[3];
  const float* pos_emb  = (const float*)d_in[4];
  const float* ln1_g    = (const float*)d_in[5];
  const float* ln1_b    = (const float*)d_in[6];
  const float* qkv_w    = (const float*)d_in[7];
  const float* qkv_b    = (const float*)d_in[8];
  const float* proj_w   = (const float*)d_in[9];
  const float* proj_b   = (const float*)d_in[10];
  const float* ln2_g    = (const float*)d_in[11];
  const float* ln2_b    = (const float*)d_in[12];
  const float* fc1_w    = (const float*)d_in[13];
  const float* fc1_b    = (const float*)d_in[14];
  const float* fc2_w    = (const float*)d_in[15];
  const float* fc2_b    = (const float*)d_in[16];
  const float* norm_g   = (const float*)d_in[17];
  const float* norm_b   = (const float*)d_in[18];
  const float* head_w   = (const float*)d_in[19];
  const float* head_b   = (const float*)d_in[20];
  float* out = (float*)d_out;

  // ---- workspace layout ----
  char* p = (char*)d_ws;
  float* tok    = (float*)p;                 p += (size_t)MTOK * D_ * 4;
  short* y_bf   = (short*)p;                 p += (size_t)MPAD * D_ * 2;
  short* o_bf   = (short*)p;                 p += (size_t)MPAD * D_ * 2;
  short* h_bf   = (short*)p;                 p += (size_t)MPAD * DFF * 2;
  short* wt_qkv = (short*)p;                 p += (size_t)D_ * 3 * D_ * 2;
  short* wt_prj = (short*)p;                 p += (size_t)D_ * D_ * 2;
  short* wt_fc1 = (short*)p;                 p += (size_t)D_ * DFF * 2;
  short* wt_fc2 = (short*)p;                 p += (size_t)DFF * D_ * 2;
  short* cw_bf  = (short*)p;                 p += (size_t)D_ * D_ * 2;
  short* im_bf  = (short*)p;                 p += (size_t)MPAD * D_ * 2;
  float* big1   = (float*)p;                 p += (size_t)MTOK * 3 * D_ * 4;
  short* qkv_bf = (short*)big1;              // M x 2304 bf16 (layer loop)
  float* pout   = big1;                      // patch gemm out (pre-loop only)
  float* fc2_part = big1;                    // 3 x M x 768 fp32 split-K partials
  float* yf     = (float*)(p);               // 32x768 fp32 final-LN out

  // ---- patch embedding ----
  cvt_kernel<<<(D_ * D_ + 255) / 256, 256, 0, stream>>>(conv_w, cw_bf, D_ * D_);
  im2col_kernel<<<(MPATCH * D_ + 255) / 256, 256, 0, stream>>>(x, im_bf);
  cls_pos_kernel<<<(B_ * D_ + 255) / 256, 256, 0, stream>>>(cls_tok, pos_emb, tok);
  {
    dim3 g(D_ / 128, MPATCH / 64);  // 6 x 98
    gemm_db_kernel<64, false, false, false><<<g, 128, 0, stream>>>(
        im_bf, cw_bf, conv_b, nullptr, pout, MPATCH, D_, D_, D_);
  }
  patch_scatter_kernel<<<(MPATCH * D_ + 255) / 256, 256, 0, stream>>>(pout, pos_emb, tok);

  dim3 gQKV(3 * D_ / 256, (MTOK + 255) / 256);     // 9 x 25  (256^2 8-phase)
  dim3 gPRJ(D_ / 128, (MTOK + 63) / 64);           // 6 x 99
  dim3 gFC1(DFF / 256, (MTOK + 255) / 256);        // 12 x 25 (256^2 8-phase)
  dim3 gFC2(D_ / 128, (MTOK + 127) / 128, 3);      // 6 x 50 x 3 (split-K)

  for (int l = 0; l < L_; l++) {
    const float* l1g = ln1_g + l * D_;
    const float* l1b = ln1_b + l * D_;
    const float* qw  = qkv_w + (size_t)l * D_ * 3 * D_;
    const float* qb  = qkv_b + (size_t)l * 3 * D_;
    const float* pw  = proj_w + (size_t)l * D_ * D_;
    const float* pb  = proj_b + (size_t)l * D_;
    const float* l2g = ln2_g + l * D_;
    const float* l2b = ln2_b + l * D_;
    const float* f1w = fc1_w + (size_t)l * D_ * DFF;
    const float* f1b = fc1_b + (size_t)l * DFF;
    const float* f2w = fc2_w + (size_t)l * DFF * D_;
    const float* f2b = fc2_b + (size_t)l * D_;

    wconv_all_kernel<<<6912, 256, 0, stream>>>(qw, pw, f1w, f2w,
                                               wt_qkv, wt_prj, wt_fc1, wt_fc2);

    ln_kernel<true><<<MTOK, 256, 0, stream>>>(tok, y_bf, l1g, l1b, D_);
    gemm256_kernel<false><<<gQKV, 512, 0, stream>>>(
        y_bf, wt_qkv, qb, qkv_bf, MTOK, 3 * D_, D_);
    attn_mfma_kernel<<<B_ * NH, 256, 0, stream>>>(qkv_bf, o_bf);
    gemm_db_kernel<64, false, true, false><<<gPRJ, 128, 0, stream>>>(
        o_bf, wt_prj, pb, tok, tok, MTOK, D_, D_, D_);
    ln_kernel<true><<<MTOK, 256, 0, stream>>>(tok, y_bf, l2g, l2b, D_);
    gemm256_kernel<true><<<gFC1, 512, 0, stream>>>(
        y_bf, wt_fc1, f1b, h_bf, MTOK, DFF, D_);
    // FC2: split-K=3 over K=3072 -> fp32 partials, then fused reduce
    gemm_db_kernel<128, false, false, false, true><<<gFC2, 256, 0, stream>>>(
        h_bf, wt_fc2, nullptr, nullptr, fc2_part, MTOK, D_, DFF, 1024);
    fc2_reduce_kernel<<<(MTOK * D_ / 4 + 255) / 256, 256, 0, stream>>>(
        fc2_part, f2b, tok);
  }

  ln_kernel<false><<<B_, 256, 0, stream>>>(tok, yf, norm_g, norm_b, (long)NTOK * D_);
  head_kernel<<<B_, 64, 0, stream>>>(yf, head_w, head_b, out);
}